// Round 2
// baseline (178.952 us; speedup 1.0000x reference)
//
#include <hip/hip_runtime.h>

#define NT 16
#define NTILES 256
#define INV_TILE (1.0f/64.0f)
#define CHUNK 1024          // points per block (k_hist/k_scatter share chunking)
#define FSTRIDE 1025        // feature plane stride (bank-conflict-free for 7-lane/j reads)

__device__ __forceinline__ int tile_of(float x, float y) {
    int tx = (int)floorf(x * INV_TILE);
    tx = tx < 0 ? 0 : (tx > NT - 1 ? NT - 1 : tx);
    int ty = (int)floorf(y * INV_TILE);
    ty = ty < 0 ? 0 : (ty > NT - 1 ? NT - 1 : ty);
    return ty * NT + tx;
}

// 64-lane same-tile group mask via 8 ballots (tile id is 8 bits).
__device__ __forceinline__ unsigned long long match_mask(int t, bool valid) {
    unsigned long long m = ~0ull;
#pragma unroll
    for (int b = 0; b < 8; ++b) {
        unsigned long long bal = __ballot((t >> b) & 1);
        m &= ((t >> b) & 1) ? bal : ~bal;
    }
    m &= __ballot(valid);
    return m;
}

// K1: counts only. Reads pos2d (coalesced), ballot-counts per wave,
// writes per-chunk per-tile totals + global per-tile atomics. No P array.
__global__ __launch_bounds__(512, 8) void k_hist(const float2* __restrict__ pos2d,
                                                 int* __restrict__ gHist,
                                                 int* __restrict__ gcounts,
                                                 int N) {
    __shared__ unsigned short cnt[8][NTILES];   // 4 KB, per-wave private
    const int tid = threadIdx.x;
    const int wl = tid >> 6, lane = tid & 63;
    const int base_i = blockIdx.x * CHUNK;
    ((int*)cnt)[tid] = 0;                       // 1024 dwords total
    ((int*)cnt)[tid + 512] = 0;
    __syncthreads();
#pragma unroll
    for (int r = 0; r < 2; ++r) {
        int o = wl * 128 + r * 64 + lane;
        int i = base_i + o;
        bool valid = i < N;
        int t = 0;
        if (valid) { float2 p = pos2d[i]; t = tile_of(p.x, p.y); }
        unsigned long long m = match_mask(t, valid);
        if (valid) {
            unsigned long long below = m & ((1ull << lane) - 1ull);
            if (below == 0ull)                  // group leader adds group size
                cnt[wl][t] = (unsigned short)(cnt[wl][t] + __popcll(m));
        }
    }
    __syncthreads();
    if (tid < NTILES) {
        int tot = 0;
#pragma unroll
        for (int w = 0; w < 8; ++w) tot += cnt[w][tid];
        gHist[(size_t)blockIdx.x * NTILES + tid] = tot;
        if (tot) atomicAdd(&gcounts[tid], tot);
    }
}

// K2: one block per tile t. Cross-tile exclusive offset + scan of per-chunk
// totals column into per-(chunk,tile) global bases, in place. NWA <= 2048.
__global__ __launch_bounds__(512) void k_scan(const int* __restrict__ gcounts,
                                              int* __restrict__ gHist,
                                              float* __restrict__ out_counts,
                                              float* __restrict__ out_offsets,
                                              int NWA) {
    const int t = blockIdx.x;
    const int tid = threadIdx.x;
    const int wl = tid >> 6, lane = tid & 63;
    __shared__ int sdata[NTILES];
    __shared__ int wsum[8];

    if (tid < NTILES) sdata[tid] = (tid < t) ? gcounts[tid] : 0;
    __syncthreads();
#pragma unroll
    for (int s = 128; s > 0; s >>= 1) {
        if (tid < s) sdata[tid] += sdata[tid + s];
        __syncthreads();
    }
    int offset_t = sdata[0];
    if (tid == 0) {
        int ct = gcounts[t];
        out_counts[t]  = (float)ct;
        out_offsets[t] = (float)offset_t;
    }

    int vals[4];
    const int base_row = tid * 4;
#pragma unroll
    for (int k = 0; k < 4; ++k) {
        int row = base_row + k;
        vals[k] = (row < NWA) ? gHist[(size_t)row * NTILES + t] : 0;
    }
    int tv = vals[0] + vals[1] + vals[2] + vals[3];
    int x = tv;
#pragma unroll
    for (int s = 1; s < 64; s <<= 1) {
        int y = __shfl_up(x, s);
        if (lane >= s) x += y;
    }
    if (lane == 63) wsum[wl] = x;
    __syncthreads();
    int wprefix = 0;
    for (int u = 0; u < wl; ++u) wprefix += wsum[u];
    int running = offset_t + wprefix + (x - tv);
#pragma unroll
    for (int k = 0; k < 4; ++k) {
        int row = base_row + k;
        if (row < NWA) gHist[(size_t)row * NTILES + t] = running;
        running += vals[k];
    }
}

// K3: all-LDS staging + float-linear coalesced write-out.
// Phase A (coalesced): read pos/cov/op, compute features -> LDS planes at
//   identity slot o; recompute tile + wave-local stable rank via ballots.
// Scan: block-local tile starts; obase[t] = gbase[t] - tstart[t].
// Phase A2: slotPk[ldest] = (t<<16)|o (the only permuted LDS write beside planes).
// Phase B: flat float index f = j*7+c -> out addr = obase[t]*7 + f, so
//   consecutive f give consecutive global addresses (coalesced dword stores).
// LDS ~39 KB -> 4 blocks/CU x 8 waves = 32 waves/CU.
__global__ __launch_bounds__(512, 8) void k_scatter(const float2* __restrict__ pos2d,
                                                    const float4* __restrict__ cov2d,
                                                    const float*  __restrict__ opacity,
                                                    const int*    __restrict__ gBase,
                                                    float* __restrict__ out_feat,
                                                    float* __restrict__ out_order,
                                                    int N) {
    __shared__ float sFeat[7 * FSTRIDE];        // 28.7 KB SoA feature planes
    __shared__ unsigned int slotPk[CHUNK];      // 4 KB: (t<<16)|o at sorted slot
    __shared__ unsigned short cnt[8][NTILES];   // 4 KB: counts, then per-wave bases
    __shared__ int base7[NTILES];               // (gbase - tstart) * 7
    __shared__ int obase[NTILES];               // (gbase - tstart)
    __shared__ int wsum[4];

    const int tid = threadIdx.x;
    const int wl = tid >> 6, lane = tid & 63;
    const int base_i = blockIdx.x * CHUNK;

    ((int*)cnt)[tid] = 0;
    ((int*)cnt)[tid + 512] = 0;
    int gb = 0;
    if (tid < NTILES) gb = gBase[(size_t)blockIdx.x * NTILES + tid];  // issue early
    __syncthreads();

    // ---- phase A: coalesced load + feature compute + ballot ranks ----
    unsigned int meta[2];
#pragma unroll
    for (int r = 0; r < 2; ++r) {
        int o = wl * 128 + r * 64 + lane;
        int i = base_i + o;
        bool valid = i < N;
        int t = 0;
        if (valid) {
            float2 p  = pos2d[i];
            float4 cv = cov2d[i];
            float op  = opacity[i];
            t = tile_of(p.x, p.y);
            float a = cv.x, b = cv.y, d = cv.w;
            float trace = a + d;
            float det = a * d - b * b;          // b == c (symmetric cov)
            float term1 = 0.5f * trace;
            float term2 = 0.5f * sqrtf(fmaxf(trace * trace - 4.0f * det, 0.0f));
            float rad = fmaxf(term1 - term2, term1 + term2);
            float inv = 1.0f / det;
            sFeat[0 * FSTRIDE + o] = p.x;
            sFeat[1 * FSTRIDE + o] = p.y;
            sFeat[2 * FSTRIDE + o] = d * inv;
            sFeat[3 * FSTRIDE + o] = -b * inv;
            sFeat[4 * FSTRIDE + o] = a * inv;
            sFeat[5 * FSTRIDE + o] = op;
            sFeat[6 * FSTRIDE + o] = rad;
        }
        unsigned long long m = match_mask(t, valid);
        unsigned int pk = 0x80000000u;          // invalid marker
        if (valid) {
            unsigned long long below = m & ((1ull << lane) - 1ull);
            int rank = __popcll(below);
            int b0 = cnt[wl][t];                // lockstep read-before-write
            if (below == 0ull) cnt[wl][t] = (unsigned short)(b0 + __popcll(m));
            pk = ((unsigned)t << 16) | (unsigned)(b0 + rank);
        }
        meta[r] = pk;
    }
    __syncthreads();

    // ---- block scan (threads 0..255, tid = tile) ----
    int tot = 0, x = 0;
    if (tid < NTILES) {
#pragma unroll
        for (int w = 0; w < 8; ++w) tot += cnt[w][tid];
        x = tot;
#pragma unroll
        for (int s = 1; s < 64; s <<= 1) {
            int y = __shfl_up(x, s);
            if (lane >= s) x += y;
        }
        if (lane == 63) wsum[wl] = x;
    }
    __syncthreads();
    if (tid < NTILES) {
        int wpre = 0;
        for (int u = 0; u < wl; ++u) wpre += wsum[u];
        int run = wpre + x - tot;               // tstart: block-excl start of tile
        int ob = gb - run;
        obase[tid] = ob;
        base7[tid] = ob * 7;
#pragma unroll
        for (int w = 0; w < 8; ++w) {           // per-wave bases, in place
            int cw = cnt[w][tid];
            cnt[w][tid] = (unsigned short)run;
            run += cw;
        }
    }
    __syncthreads();

    // ---- phase A2: write permutation plane ----
#pragma unroll
    for (int r = 0; r < 2; ++r) {
        unsigned int pk = meta[r];
        if (!(pk & 0x80000000u)) {
            int o = wl * 128 + r * 64 + lane;
            int t  = pk >> 16;
            int pw = pk & 0xFFFF;
            int ldest = cnt[wl][t] + pw;
            slotPk[ldest] = ((unsigned)t << 16) | (unsigned)o;
        }
    }
    __syncthreads();

    // ---- phase B: float-linear coalesced write-out ----
    int nvalid = N - base_i; if (nvalid > CHUNK) nvalid = CHUNK;
    int nv7 = nvalid * 7;
    {
        // f = tid + k*512; maintain j = f/7, c = f%7 incrementally (512 = 73*7+1)
        int j = (int)((unsigned)tid / 7u);
        int c = tid - 7 * j;
        for (int f = tid; f < nv7; f += 512) {
            unsigned int pk = slotPk[j];        // broadcast among 7 lanes sharing j
            int t = pk >> 16;
            int o = pk & 0xFFFF;
            out_feat[(size_t)(base7[t] + f)] = sFeat[c * FSTRIDE + o];
            j += 73; c += 1;
            if (c >= 7) { c -= 7; j += 1; }
        }
    }
    for (int j = tid; j < nvalid; j += 512) {
        unsigned int pk = slotPk[j];
        out_order[obase[pk >> 16] + j] = (float)(base_i + (int)(pk & 0xFFFF));
    }
}

extern "C" void kernel_launch(void* const* d_in, const int* in_sizes, int n_in,
                              void* d_out, int out_size, void* d_ws, size_t ws_size,
                              hipStream_t stream) {
    const float2* pos2d   = (const float2*)d_in[0];
    const float4* cov2d   = (const float4*)d_in[1];
    const float*  opacity = (const float*)d_in[2];
    const int N = in_sizes[2];           // opacity element count

    float* out         = (float*)d_out;  // layout: feat | counts | offsets | order
    float* out_feat    = out;
    float* out_counts  = out + (size_t)N * 7;
    float* out_offsets = out_counts + NTILES;
    float* out_order   = out_offsets + NTILES;

    int nchunks = (N + CHUNK - 1) / CHUNK;   // 1954 for N=2M (k_scan supports <=2048)

    int* gcounts = (int*)d_ws;               // [256]
    int* gHist   = gcounts + NTILES;         // [nchunks x 256] totals -> bases

    hipMemsetAsync(gcounts, 0, NTILES * sizeof(int), stream);
    k_hist<<<nchunks, 512, 0, stream>>>(pos2d, gHist, gcounts, N);
    k_scan<<<NTILES, 512, 0, stream>>>(gcounts, gHist, out_counts, out_offsets, nchunks);
    k_scatter<<<nchunks, 512, 0, stream>>>(pos2d, cov2d, opacity, gHist,
                                           out_feat, out_order, N);
}